// Round 4
// baseline (612.700 us; speedup 1.0000x reference)
//
#include <hip/hip_runtime.h>
#include <hip/hip_bf16.h>

#define BB 16
#define CIN 256
#define DD 256
#define HH 96
#define NPIX 9216
#define HEADS 8
#define HD 32
#define MM 4

typedef short bf16x8 __attribute__((ext_vector_type(8)));
typedef float f32x4 __attribute__((ext_vector_type(4)));

__device__ __forceinline__ float b2f(unsigned u) {
    unsigned x = u << 16;
    return __builtin_bit_cast(float, x);
}
__device__ __forceinline__ ushort f2b(float f) {
    unsigned x = __builtin_bit_cast(unsigned, f);
    unsigned r = (x + 0x7FFF + ((x >> 16) & 1)) >> 16;  // RNE
    return (ushort)r;
}
__device__ __forceinline__ void unpack8(uint4 q, float* f) {
    f[0] = b2f(q.x & 0xffffu); f[1] = b2f(q.x >> 16);
    f[2] = b2f(q.y & 0xffffu); f[3] = b2f(q.y >> 16);
    f[4] = b2f(q.z & 0xffffu); f[5] = b2f(q.z >> 16);
    f[6] = b2f(q.w & 0xffffu); f[7] = b2f(q.w >> 16);
}
__device__ __forceinline__ void gload16(const ushort* g, ushort* l) {
    __builtin_amdgcn_global_load_lds(
        (const __attribute__((address_space(1))) unsigned int*)g,
        (__attribute__((address_space(3))) unsigned int*)l, 16, 0, 0);
}

// ---------------------------------------------------------------------------
// cvt: Wf,Wv,Wp f32 -> bf16 concat buffer wb [3*65536]
// ---------------------------------------------------------------------------
__global__ __launch_bounds__(256) void cvt_kernel(const float* __restrict__ Wf,
                                                  const float* __restrict__ Wv,
                                                  const float* __restrict__ Wp,
                                                  ushort* __restrict__ wb) {
    int i = (blockIdx.x * 256 + threadIdx.x) * 4;
    float4 v;
    if (i < 65536) v = *(const float4*)(Wf + i);
    else if (i < 131072) v = *(const float4*)(Wv + (i - 65536));
    else v = *(const float4*)(Wp + (i - 131072));
    ushort4 o;
    o.x = f2b(v.x); o.y = f2b(v.y); o.z = f2b(v.z); o.w = f2b(v.w);
    *(ushort4*)(wb + i) = o;
}

// ---------------------------------------------------------------------------
// prep: G[e*4+m][c] = sum_d cn[m][d]*Wf[e*32+d][c];  gb[e*4+m] = sum_d cn[m][d]*bf[e*32+d]
// ---------------------------------------------------------------------------
__global__ __launch_bounds__(256) void prep_kernel(const float* __restrict__ Wf,
                                                   const float* __restrict__ bfp,
                                                   const float* __restrict__ centers,
                                                   float* __restrict__ G,
                                                   float* __restrict__ gb) {
    __shared__ float cns[4][32];
    int t = threadIdx.x;
    if (t < 4) {
        float c[32]; float s = 0.f;
        for (int d = 0; d < 32; ++d) { c[d] = centers[t * 32 + d]; s += c[d] * c[d]; }
        float inv = 1.f / fmaxf(sqrtf(s), 1e-12f);
        for (int d = 0; d < 32; ++d) cns[t][d] = c[d] * inv;
    }
    __syncthreads();
    for (int i = t; i < 8192; i += 256) {
        int em = i >> 8, c = i & 255;
        int e = em >> 2, m = em & 3;
        float s = 0.f;
        for (int d = 0; d < 32; ++d) s += cns[m][d] * Wf[(e * 32 + d) * 256 + c];
        G[i] = s;
    }
    if (t < 32) {
        int e = t >> 2, m = t & 3;
        float s = 0.f;
        for (int d = 0; d < 32; ++d) s += cns[m][d] * bfp[e * 32 + d];
        gb[t] = s;
    }
}

// ---------------------------------------------------------------------------
// tr: x [b,c,n] f32 -> xT [b,n,c] bf16
// ---------------------------------------------------------------------------
__global__ __launch_bounds__(256) void tr_kernel(const float* __restrict__ x,
                                                 ushort* __restrict__ xT) {
    __shared__ ushort tile[64][74];
    int nt = blockIdx.x, ct = blockIdx.y, b = blockIdx.z;
    int n0 = nt * 64, c0 = ct * 64;
    int t = threadIdx.x;
#pragma unroll
    for (int p = 0; p < 4; ++p) {
        int ch = t + p * 256;                  // 1024 chunks of 4 floats
        int c = ch >> 4, no = (ch & 15) * 4;
        float4 v = *(const float4*)(x + ((size_t)(b * CIN + c0 + c)) * NPIX + n0 + no);
        ushort2 lo, hi;
        lo.x = f2b(v.x); lo.y = f2b(v.y); hi.x = f2b(v.z); hi.y = f2b(v.w);
        *(ushort2*)&tile[c][no] = lo;
        *(ushort2*)&tile[c][no + 2] = hi;
    }
    __syncthreads();
#pragma unroll
    for (int p = 0; p < 2; ++p) {
        int ch = t + p * 256;                  // 512 chunks of 8 bf16 along c
        int n = ch >> 3, co = (ch & 7) * 8;
        uint4 val; ushort* tp = (ushort*)&val;
#pragma unroll
        for (int j = 0; j < 8; ++j) tp[j] = tile[co + j][n];
        *(uint4*)(xT + ((size_t)(b * NPIX + n0 + n)) * CIN + c0 + co) = val;
    }
}

// ---------------------------------------------------------------------------
// gmap: per (b,n) compute 32 f32 logits g = G*x(n)+gb; per head e: argmax_m of
// alpha*g and the winning value. Exact-precision argmax path.
// ---------------------------------------------------------------------------
__global__ __launch_bounds__(256) void gmap_kernel(const float* __restrict__ x,
                                                   const float* __restrict__ G,
                                                   const float* __restrict__ gb,
                                                   const float* __restrict__ alpha_p,
                                                   unsigned char* __restrict__ idxg,
                                                   float* __restrict__ zbest) {
    __shared__ float Gs[32][256];
    __shared__ float gbs[32];
    int b = blockIdx.y;
    int t = threadIdx.x;
    int n = blockIdx.x * 256 + t;
    for (int i = t; i < 8192; i += 256) Gs[i >> 8][i & 255] = G[i];
    if (t < 32) gbs[t] = gb[t];
    __syncthreads();
    float acc[32];
#pragma unroll
    for (int em = 0; em < 32; ++em) acc[em] = gbs[em];
    const float* xb = x + (size_t)b * CIN * NPIX + n;
#pragma unroll 4
    for (int c = 0; c < 256; ++c) {
        float xv = xb[(size_t)c * NPIX];
#pragma unroll
        for (int em = 0; em < 32; ++em) acc[em] = fmaf(Gs[em][c], xv, acc[em]);
    }
    float alpha = alpha_p[0];
#pragma unroll
    for (int e = 0; e < 8; ++e) {
        float z0 = alpha * acc[e * 4 + 0], z1 = alpha * acc[e * 4 + 1];
        float z2 = alpha * acc[e * 4 + 2], z3 = alpha * acc[e * 4 + 3];
        int bm = 0; float bz = z0;
        if (z1 > bz) { bz = z1; bm = 1; }
        if (z2 > bz) { bz = z2; bm = 2; }
        if (z3 > bz) { bz = z3; bm = 3; }
        size_t o = ((size_t)(b * 8 + e)) * NPIX + n;
        idxg[o] = (unsigned char)bm;
        zbest[o] = bz;
    }
}

// ---------------------------------------------------------------------------
// GEMM main loop: C[128x128] = A[128xK=256] * B^T (both rows k-contiguous)
// ---------------------------------------------------------------------------
__device__ __forceinline__ void gemm_main(const ushort* A, const ushort* Bp,
                                          ushort* lA, ushort* lB,
                                          f32x4 acc[4][4],
                                          int wr, int wc, int lane, int wave, int t) {
    const ushort* aSrc = A + (t >> 2) * 256 + (t & 3) * 8;
    const ushort* bSrc = Bp + (t >> 2) * 256 + (t & 3) * 8;
    ushort* la0 = lA + wave * 512;
    ushort* lb0 = lB + wave * 512;
    int l15 = lane & 15, g8 = (lane >> 4) * 8;
    for (int k0 = 0; k0 < 256; k0 += 32) {
        gload16(aSrc + k0, la0);
        gload16(aSrc + 64 * 256 + k0, la0 + 2048);
        gload16(bSrc + k0, lb0);
        gload16(bSrc + 64 * 256 + k0, lb0 + 2048);
        __syncthreads();
        bf16x8 af[4], bb[4];
#pragma unroll
        for (int i = 0; i < 4; ++i) {
            af[i] = *(const bf16x8*)(lA + (wr * 64 + i * 16 + l15) * 32 + g8);
            bb[i] = *(const bf16x8*)(lB + (wc * 64 + i * 16 + l15) * 32 + g8);
        }
#pragma unroll
        for (int i = 0; i < 4; ++i)
#pragma unroll
            for (int j = 0; j < 4; ++j)
                acc[i][j] = __builtin_amdgcn_mfma_f32_16x16x32_bf16(af[i], bb[j], acc[i][j], 0, 0, 0);
        __syncthreads();
    }
}

// ---------------------------------------------------------------------------
// gemm_fv: fv[b][n][512] bf16  (0..255 feat, 256..511 value)
// ---------------------------------------------------------------------------
__global__ __launch_bounds__(256, 2) void gemm_fv(const ushort* __restrict__ wb,
                                                  const float* __restrict__ bfp,
                                                  const float* __restrict__ bvp,
                                                  const ushort* __restrict__ xT,
                                                  ushort* __restrict__ fv) {
    __shared__ ushort lA[128 * 32];
    __shared__ ushort lB[128 * 32];
    int nt = blockIdx.x, mt = blockIdx.y, b = blockIdx.z;
    int t = threadIdx.x;
    int wave = t >> 6, lane = t & 63;
    int wr = wave >> 1, wc = wave & 1;
    const ushort* A = wb + (size_t)mt * 128 * 256;   // mt 0,1: Wf; 2,3: Wv
    const ushort* Bp = xT + (size_t)b * NPIX * CIN + (size_t)nt * 128 * CIN;
    f32x4 acc[4][4] = {};
    gemm_main(A, Bp, lA, lB, acc, wr, wc, lane, wave, t);

    const float* bias = (mt < 2) ? (bfp + mt * 128) : (bvp + (mt - 2) * 128);
    int l15 = lane & 15, rg = lane >> 4;
    size_t rowbase = (size_t)b * NPIX;
#pragma unroll
    for (int i = 0; i < 4; ++i) {
        int o_l = wr * 64 + i * 16 + rg * 4;
        float bi0 = bias[o_l + 0], bi1 = bias[o_l + 1];
        float bi2 = bias[o_l + 2], bi3 = bias[o_l + 3];
#pragma unroll
        for (int j = 0; j < 4; ++j) {
            int n = nt * 128 + wc * 64 + j * 16 + l15;
            unsigned lo = (unsigned)f2b(acc[i][j][0] + bi0) | ((unsigned)f2b(acc[i][j][1] + bi1) << 16);
            unsigned hi = (unsigned)f2b(acc[i][j][2] + bi2) | ((unsigned)f2b(acc[i][j][3] + bi3) << 16);
            *(uint2*)(fv + ((rowbase + n) << 9) + mt * 128 + o_l) = make_uint2(lo, hi);
        }
    }
}

// ---------------------------------------------------------------------------
// cluster: per (b,e): sg from zbest/|f|, aggregate value, dispatch op bf16
// ---------------------------------------------------------------------------
__global__ __launch_bounds__(256, 1) void cluster_kernel(const ushort* __restrict__ fv,
                                                         const unsigned char* __restrict__ idxg,
                                                         const float* __restrict__ zbest,
                                                         const float* __restrict__ beta_p,
                                                         ushort* __restrict__ op,
                                                         float* __restrict__ mapo) {
    __shared__ float simv[NPIX];
    __shared__ unsigned char idx8[NPIX];
    __shared__ float wred[4][136];
    __shared__ float tot[136];
    __shared__ float agg[4][32];
    int be = blockIdx.x;
    int b = be >> 3, e = be & 7;
    int t = threadIdx.x;
    float beta = beta_p[0];
    float acc[4][32] = {};
    float den[4] = {};
    const ushort* fvb = fv + (size_t)b * NPIX * 512;
    const unsigned char* ib = idxg + (size_t)be * NPIX;
    const float* zb = zbest + (size_t)be * NPIX;

    for (int n = t; n < NPIX; n += 256) {
        const uint4* fq = (const uint4*)(fvb + ((size_t)n << 9) + e * 32);
        float f[32];
        unpack8(fq[0], f); unpack8(fq[1], f + 8); unpack8(fq[2], f + 16); unpack8(fq[3], f + 24);
        float nr = 0.f;
#pragma unroll
        for (int d = 0; d < 32; ++d) nr += f[d] * f[d];
        float inv = 1.f / fmaxf(sqrtf(nr), 1e-12f);
        int bm = ib[n];
        float z = beta + zb[n] * inv;
        float sg = 1.f / (1.f + __expf(-z));
        simv[n] = sg;
        idx8[n] = (unsigned char)bm;

        const uint4* vq = (const uint4*)(fvb + ((size_t)n << 9) + 256 + e * 32);
        float v[32];
        unpack8(vq[0], v); unpack8(vq[1], v + 8); unpack8(vq[2], v + 16); unpack8(vq[3], v + 24);
        int h = n / HH, w = n - h * HH;
        int mq = ((h >= 48) ? 2 : 0) + ((w >= 48) ? 1 : 0);
#pragma unroll
        for (int m = 0; m < 4; ++m) {
            float wm = ((bm == m) ? sg : 0.f) + ((mq == m) ? (1.f / 2304.f) : 0.f);
#pragma unroll
            for (int d = 0; d < 32; ++d) acc[m][d] = fmaf(wm, v[d], acc[m][d]);
            den[m] += (bm == m) ? sg : 0.f;
        }
    }

    int wave = t >> 6, lane = t & 63;
#pragma unroll
    for (int m = 0; m < 4; ++m) {
#pragma unroll
        for (int d = 0; d < 32; ++d) {
            float v_ = acc[m][d];
#pragma unroll
            for (int off = 32; off >= 1; off >>= 1) v_ += __shfl_xor(v_, off, 64);
            if (lane == 0) wred[wave][m * 32 + d] = v_;
        }
        float dv = den[m];
#pragma unroll
        for (int off = 32; off >= 1; off >>= 1) dv += __shfl_xor(dv, off, 64);
        if (lane == 0) wred[wave][128 + m] = dv;
    }
    __syncthreads();
    if (t < 132) tot[t] = wred[0][t] + wred[1][t] + wred[2][t] + wred[3][t];
    __syncthreads();
    if (t < 128) {
        int m = t >> 5, d = t & 31;
        agg[m][d] = tot[t] / (tot[128 + m] + 1.0f);
    }
    __syncthreads();

    ushort* opb = op + (size_t)b * NPIX * DD;
    for (int n = t; n < NPIX; n += 256) {
        float sg = simv[n];
        int m = idx8[n];
        const float* ag = agg[m];
        unsigned wds[16];
#pragma unroll
        for (int d2 = 0; d2 < 16; ++d2)
            wds[d2] = (unsigned)f2b(sg * ag[2 * d2]) | ((unsigned)f2b(sg * ag[2 * d2 + 1]) << 16);
        uint4* dst = (uint4*)(opb + (size_t)n * DD + e * 32);
        dst[0] = make_uint4(wds[0], wds[1], wds[2], wds[3]);
        dst[1] = make_uint4(wds[4], wds[5], wds[6], wds[7]);
        dst[2] = make_uint4(wds[8], wds[9], wds[10], wds[11]);
        dst[3] = make_uint4(wds[12], wds[13], wds[14], wds[15]);
    }
    if (be == 0) {
        for (int n = t; n < NPIX; n += 256) mapo[n] = (float)idx8[n];
    }
}

// ---------------------------------------------------------------------------
// gemm_p: out[b][o][n] f32 = Wp * op + bp
// ---------------------------------------------------------------------------
__global__ __launch_bounds__(256, 2) void gemm_p(const ushort* __restrict__ wb,
                                                 const float* __restrict__ bpp,
                                                 const ushort* __restrict__ opm,
                                                 float* __restrict__ out) {
    __shared__ ushort lA[128 * 32];
    __shared__ ushort lB[128 * 32];
    int nt = blockIdx.x, mt = blockIdx.y, b = blockIdx.z;
    int t = threadIdx.x;
    int wave = t >> 6, lane = t & 63;
    int wr = wave >> 1, wc = wave & 1;
    const ushort* A = wb + 131072 + (size_t)mt * 128 * 256;  // Wp
    const ushort* Bp = opm + (size_t)b * NPIX * DD + (size_t)nt * 128 * DD;
    f32x4 acc[4][4] = {};
    gemm_main(A, Bp, lA, lB, acc, wr, wc, lane, wave, t);

    int l15 = lane & 15, rg = lane >> 4;
#pragma unroll
    for (int i = 0; i < 4; ++i) {
        int o = mt * 128 + wr * 64 + i * 16 + rg * 4;
        float bi0 = bpp[o + 0], bi1 = bpp[o + 1], bi2 = bpp[o + 2], bi3 = bpp[o + 3];
#pragma unroll
        for (int j = 0; j < 4; ++j) {
            int n = nt * 128 + wc * 64 + j * 16 + l15;
            size_t base = ((size_t)b * 256 + o) * NPIX + n;
            out[base + 0 * (size_t)NPIX] = acc[i][j][0] + bi0;
            out[base + 1 * (size_t)NPIX] = acc[i][j][1] + bi1;
            out[base + 2 * (size_t)NPIX] = acc[i][j][2] + bi2;
            out[base + 3 * (size_t)NPIX] = acc[i][j][3] + bi3;
        }
    }
}

// ---------------------------------------------------------------------------
extern "C" void kernel_launch(void* const* d_in, const int* in_sizes, int n_in,
                              void* d_out, int out_size, void* d_ws, size_t ws_size,
                              hipStream_t stream) {
    const float* x   = (const float*)d_in[0];
    const float* Wf  = (const float*)d_in[1];
    const float* bfp = (const float*)d_in[2];
    const float* Wv  = (const float*)d_in[3];
    const float* bvp = (const float*)d_in[4];
    const float* Wp  = (const float*)d_in[5];
    const float* bpp = (const float*)d_in[6];
    const float* al  = (const float*)d_in[7];
    const float* bt  = (const float*)d_in[8];
    const float* ce  = (const float*)d_in[9];
    float* out = (float*)d_out;

    // Workspace (bytes):
    //   xT (bf16, 75.5MB) -- reused as op after gemm_fv consumes it
    //   wb (bf16 weights) | G | gb | idxg | zbest
    char* ws = (char*)d_ws;
    ushort* xT   = (ushort*)ws;                                  // 75,497,472 B
    ushort* op   = xT;
    ushort* wbuf = (ushort*)(ws + 75497472);                     //    393,216 B
    float*  G    = (float*)(ws + 75890688);                      //     32,768 B
    float*  gb   = (float*)(ws + 75923456);                      //        256 B
    unsigned char* idxg = (unsigned char*)(ws + 75923712);       //  1,179,648 B
    float*  zbest = (float*)(ws + 77103360);                     //  4,718,592 B -> 81,821,952 total

    // fv (bf16, 151MB) lives in d_out; fully consumed before gemm_p overwrites.
    ushort* fv = (ushort*)d_out;
    float* mapo = out + (size_t)BB * DD * NPIX;

    cvt_kernel<<<dim3(192), 256, 0, stream>>>(Wf, Wv, Wp, wbuf);
    prep_kernel<<<dim3(1), 256, 0, stream>>>(Wf, bfp, ce, G, gb);
    tr_kernel<<<dim3(144, 4, BB), 256, 0, stream>>>(x, xT);
    gmap_kernel<<<dim3(36, BB), 256, 0, stream>>>(x, G, gb, al, idxg, zbest);
    gemm_fv<<<dim3(72, 4, BB), 256, 0, stream>>>(wbuf, bfp, bvp, xT, fv);
    cluster_kernel<<<dim3(128), 256, 0, stream>>>(fv, idxg, zbest, bt, op, mapo);
    gemm_p<<<dim3(72, 2, BB), 256, 0, stream>>>(wbuf, bpp, op, out);
}

// Round 5
// 500.453 us; speedup vs baseline: 1.2243x; 1.2243x over previous
//
#include <hip/hip_runtime.h>
#include <hip/hip_bf16.h>

#define BB 16
#define CIN 256
#define DD 256
#define HH 96
#define NPIX 9216
#define HEADS 8
#define HD 32
#define MM 4

typedef short bf16x8 __attribute__((ext_vector_type(8)));
typedef float f32x4 __attribute__((ext_vector_type(4)));

__device__ __forceinline__ float b2f(unsigned u) {
    unsigned x = u << 16;
    return __builtin_bit_cast(float, x);
}
__device__ __forceinline__ ushort f2b(float f) {
    unsigned x = __builtin_bit_cast(unsigned, f);
    unsigned r = (x + 0x7FFF + ((x >> 16) & 1)) >> 16;  // RNE
    return (ushort)r;
}
__device__ __forceinline__ void unpack8(uint4 q, float* f) {
    f[0] = b2f(q.x & 0xffffu); f[1] = b2f(q.x >> 16);
    f[2] = b2f(q.y & 0xffffu); f[3] = b2f(q.y >> 16);
    f[4] = b2f(q.z & 0xffffu); f[5] = b2f(q.z >> 16);
    f[6] = b2f(q.w & 0xffffu); f[7] = b2f(q.w >> 16);
}
__device__ __forceinline__ void gload16(const ushort* g, ushort* l) {
    __builtin_amdgcn_global_load_lds(
        (const __attribute__((address_space(1))) unsigned int*)g,
        (__attribute__((address_space(3))) unsigned int*)l, 16, 0, 0);
}

// ---------------------------------------------------------------------------
// cvt: Wf,Wv,Wp f32 -> bf16 concat buffer wb [3*65536]
// ---------------------------------------------------------------------------
__global__ __launch_bounds__(256) void cvt_kernel(const float* __restrict__ Wf,
                                                  const float* __restrict__ Wv,
                                                  const float* __restrict__ Wp,
                                                  ushort* __restrict__ wb) {
    int i = (blockIdx.x * 256 + threadIdx.x) * 4;
    float4 v;
    if (i < 65536) v = *(const float4*)(Wf + i);
    else if (i < 131072) v = *(const float4*)(Wv + (i - 65536));
    else v = *(const float4*)(Wp + (i - 131072));
    ushort4 o;
    o.x = f2b(v.x); o.y = f2b(v.y); o.z = f2b(v.z); o.w = f2b(v.w);
    *(ushort4*)(wb + i) = o;
}

// ---------------------------------------------------------------------------
// prep: G[e*4+m][c] = sum_d cn[m][d]*Wf[e*32+d][c];  gb[e*4+m] = sum_d cn[m][d]*bf[e*32+d]
// ---------------------------------------------------------------------------
__global__ __launch_bounds__(256) void prep_kernel(const float* __restrict__ Wf,
                                                   const float* __restrict__ bfp,
                                                   const float* __restrict__ centers,
                                                   float* __restrict__ G,
                                                   float* __restrict__ gb) {
    __shared__ float cns[4][32];
    int t = threadIdx.x;
    if (t < 4) {
        float c[32]; float s = 0.f;
        for (int d = 0; d < 32; ++d) { c[d] = centers[t * 32 + d]; s += c[d] * c[d]; }
        float inv = 1.f / fmaxf(sqrtf(s), 1e-12f);
        for (int d = 0; d < 32; ++d) cns[t][d] = c[d] * inv;
    }
    __syncthreads();
    for (int i = t; i < 8192; i += 256) {
        int em = i >> 8, c = i & 255;
        int e = em >> 2, m = em & 3;
        float s = 0.f;
        for (int d = 0; d < 32; ++d) s += cns[m][d] * Wf[(e * 32 + d) * 256 + c];
        G[i] = s;
    }
    if (t < 32) {
        int e = t >> 2, m = t & 3;
        float s = 0.f;
        for (int d = 0; d < 32; ++d) s += cns[m][d] * bfp[e * 32 + d];
        gb[t] = s;
    }
}

// ---------------------------------------------------------------------------
// tr: x [b,c,n] f32 -> xT [b,n,c] bf16
// ---------------------------------------------------------------------------
__global__ __launch_bounds__(256) void tr_kernel(const float* __restrict__ x,
                                                 ushort* __restrict__ xT) {
    __shared__ ushort tile[64][74];
    int nt = blockIdx.x, ct = blockIdx.y, b = blockIdx.z;
    int n0 = nt * 64, c0 = ct * 64;
    int t = threadIdx.x;
#pragma unroll
    for (int p = 0; p < 4; ++p) {
        int ch = t + p * 256;                  // 1024 chunks of 4 floats
        int c = ch >> 4, no = (ch & 15) * 4;
        float4 v = *(const float4*)(x + ((size_t)(b * CIN + c0 + c)) * NPIX + n0 + no);
        ushort2 lo, hi;
        lo.x = f2b(v.x); lo.y = f2b(v.y); hi.x = f2b(v.z); hi.y = f2b(v.w);
        *(ushort2*)&tile[c][no] = lo;
        *(ushort2*)&tile[c][no + 2] = hi;
    }
    __syncthreads();
#pragma unroll
    for (int p = 0; p < 2; ++p) {
        int ch = t + p * 256;                  // 512 chunks of 8 bf16 along c
        int n = ch >> 3, co = (ch & 7) * 8;
        uint4 val; ushort* tp = (ushort*)&val;
#pragma unroll
        for (int j = 0; j < 8; ++j) tp[j] = tile[co + j][n];
        *(uint4*)(xT + ((size_t)(b * NPIX + n0 + n)) * CIN + c0 + co) = val;
    }
}

// ---------------------------------------------------------------------------
// gmap: per (b,n) compute 32 f32 logits g = G*x(n)+gb; per head e: argmax_m of
// alpha*g and the winning value. Exact-precision argmax path.
// ---------------------------------------------------------------------------
__global__ __launch_bounds__(256) void gmap_kernel(const float* __restrict__ x,
                                                   const float* __restrict__ G,
                                                   const float* __restrict__ gb,
                                                   const float* __restrict__ alpha_p,
                                                   unsigned char* __restrict__ idxg,
                                                   float* __restrict__ zbest) {
    __shared__ float Gs[32][256];
    __shared__ float gbs[32];
    int b = blockIdx.y;
    int t = threadIdx.x;
    int n = blockIdx.x * 256 + t;
    for (int i = t; i < 8192; i += 256) Gs[i >> 8][i & 255] = G[i];
    if (t < 32) gbs[t] = gb[t];
    __syncthreads();
    float acc[32];
#pragma unroll
    for (int em = 0; em < 32; ++em) acc[em] = gbs[em];
    const float* xb = x + (size_t)b * CIN * NPIX + n;
#pragma unroll 4
    for (int c = 0; c < 256; ++c) {
        float xv = xb[(size_t)c * NPIX];
#pragma unroll
        for (int em = 0; em < 32; ++em) acc[em] = fmaf(Gs[em][c], xv, acc[em]);
    }
    float alpha = alpha_p[0];
#pragma unroll
    for (int e = 0; e < 8; ++e) {
        float z0 = alpha * acc[e * 4 + 0], z1 = alpha * acc[e * 4 + 1];
        float z2 = alpha * acc[e * 4 + 2], z3 = alpha * acc[e * 4 + 3];
        int bm = 0; float bz = z0;
        if (z1 > bz) { bz = z1; bm = 1; }
        if (z2 > bz) { bz = z2; bm = 2; }
        if (z3 > bz) { bz = z3; bm = 3; }
        size_t o = ((size_t)(b * 8 + e)) * NPIX + n;
        idxg[o] = (unsigned char)bm;
        zbest[o] = bz;
    }
}

// ---------------------------------------------------------------------------
// GEMM main loop: C[128x128] = A[128xK=256] * B^T (both rows k-contiguous)
// ---------------------------------------------------------------------------
__device__ __forceinline__ void gemm_main(const ushort* A, const ushort* Bp,
                                          ushort* lA, ushort* lB,
                                          f32x4 acc[4][4],
                                          int wr, int wc, int lane, int wave, int t) {
    const ushort* aSrc = A + (t >> 2) * 256 + (t & 3) * 8;
    const ushort* bSrc = Bp + (t >> 2) * 256 + (t & 3) * 8;
    ushort* la0 = lA + wave * 512;
    ushort* lb0 = lB + wave * 512;
    int l15 = lane & 15, g8 = (lane >> 4) * 8;
    for (int k0 = 0; k0 < 256; k0 += 32) {
        gload16(aSrc + k0, la0);
        gload16(aSrc + 64 * 256 + k0, la0 + 2048);
        gload16(bSrc + k0, lb0);
        gload16(bSrc + 64 * 256 + k0, lb0 + 2048);
        __syncthreads();
        bf16x8 af[4], bb[4];
#pragma unroll
        for (int i = 0; i < 4; ++i) {
            af[i] = *(const bf16x8*)(lA + (wr * 64 + i * 16 + l15) * 32 + g8);
            bb[i] = *(const bf16x8*)(lB + (wc * 64 + i * 16 + l15) * 32 + g8);
        }
#pragma unroll
        for (int i = 0; i < 4; ++i)
#pragma unroll
            for (int j = 0; j < 4; ++j)
                acc[i][j] = __builtin_amdgcn_mfma_f32_16x16x32_bf16(af[i], bb[j], acc[i][j], 0, 0, 0);
        __syncthreads();
    }
}

// ---------------------------------------------------------------------------
// gemm_fv: head-major fv: fv[((b*8+e)*2+s)][n][32], s=0 feat, s=1 value (bf16)
// ---------------------------------------------------------------------------
__global__ __launch_bounds__(256, 2) void gemm_fv(const ushort* __restrict__ wb,
                                                  const float* __restrict__ bfp,
                                                  const float* __restrict__ bvp,
                                                  const ushort* __restrict__ xT,
                                                  ushort* __restrict__ fv) {
    __shared__ ushort lA[128 * 32];
    __shared__ ushort lB[128 * 32];
    int nt = blockIdx.x, mt = blockIdx.y, b = blockIdx.z;
    int t = threadIdx.x;
    int wave = t >> 6, lane = t & 63;
    int wr = wave >> 1, wc = wave & 1;
    const ushort* A = wb + (size_t)mt * 128 * 256;   // mt 0,1: Wf; 2,3: Wv
    const ushort* Bp = xT + (size_t)b * NPIX * CIN + (size_t)nt * 128 * CIN;
    f32x4 acc[4][4] = {};
    gemm_main(A, Bp, lA, lB, acc, wr, wc, lane, wave, t);

    const float* bias = (mt < 2) ? (bfp + mt * 128) : (bvp + (mt - 2) * 128);
    int l15 = lane & 15, rg = lane >> 4;
#pragma unroll
    for (int i = 0; i < 4; ++i) {
        int o_l = wr * 64 + i * 16 + rg * 4;
        int c = mt * 128 + o_l;            // global channel 0..511
        int s = c >> 8;                    // 0 = feat, 1 = value
        int cc = c & 255;
        int e = cc >> 5, d0 = cc & 31;
        ushort* dstb = fv + ((size_t)((b * 8 + e) * 2 + s) * NPIX) * 32 + d0;
        float bi0 = bias[o_l + 0], bi1 = bias[o_l + 1];
        float bi2 = bias[o_l + 2], bi3 = bias[o_l + 3];
#pragma unroll
        for (int j = 0; j < 4; ++j) {
            int n = nt * 128 + wc * 64 + j * 16 + l15;
            unsigned lo = (unsigned)f2b(acc[i][j][0] + bi0) | ((unsigned)f2b(acc[i][j][1] + bi1) << 16);
            unsigned hi = (unsigned)f2b(acc[i][j][2] + bi2) | ((unsigned)f2b(acc[i][j][3] + bi3) << 16);
            *(uint2*)(dstb + (size_t)n * 32) = make_uint2(lo, hi);
        }
    }
}

// ---------------------------------------------------------------------------
// cluster_reduce: grid (9 chunks, 128 be). Per-chunk partial sums + sg in-place.
//   zsg: in = zbest (winning logit), out = sg (sigmoid value), same buffer.
//   partial[be][chunk][0..127] = sum sg*v (+quadrant means), [128..131] = den.
// ---------------------------------------------------------------------------
__global__ __launch_bounds__(256, 2) void cluster_reduce(const ushort* __restrict__ fv,
                                                         const unsigned char* __restrict__ idxg,
                                                         float* __restrict__ zsg,
                                                         const float* __restrict__ beta_p,
                                                         float* __restrict__ partial) {
    __shared__ float wred[4][136];
    int chunk = blockIdx.x, be = blockIdx.y;
    int t = threadIdx.x;
    float beta = beta_p[0];
    float acc[4][32] = {};
    float den[4] = {};
    const ushort* fb = fv + ((size_t)(be * 2) * NPIX) * 32;       // feat
    const ushort* vb = fv + ((size_t)(be * 2 + 1) * NPIX) * 32;   // value
    const unsigned char* ib = idxg + (size_t)be * NPIX;
    float* zb = zsg + (size_t)be * NPIX;
    int n0 = chunk * 1024;
#pragma unroll
    for (int p = 0; p < 4; ++p) {
        int n = n0 + p * 256 + t;
        const uint4* fq = (const uint4*)(fb + (size_t)n * 32);
        float f[32];
        unpack8(fq[0], f); unpack8(fq[1], f + 8); unpack8(fq[2], f + 16); unpack8(fq[3], f + 24);
        float nr = 0.f;
#pragma unroll
        for (int d = 0; d < 32; ++d) nr += f[d] * f[d];
        float inv = 1.f / fmaxf(sqrtf(nr), 1e-12f);
        float sg = 1.f / (1.f + __expf(-(beta + zb[n] * inv)));
        zb[n] = sg;
        int bm = ib[n];
        const uint4* vq = (const uint4*)(vb + (size_t)n * 32);
        float v[32];
        unpack8(vq[0], v); unpack8(vq[1], v + 8); unpack8(vq[2], v + 16); unpack8(vq[3], v + 24);
        int h = n / HH, w = n - h * HH;
        int mq = ((h >= 48) ? 2 : 0) + ((w >= 48) ? 1 : 0);
#pragma unroll
        for (int m = 0; m < 4; ++m) {
            float wm = ((bm == m) ? sg : 0.f) + ((mq == m) ? (1.f / 2304.f) : 0.f);
#pragma unroll
            for (int d = 0; d < 32; ++d) acc[m][d] = fmaf(wm, v[d], acc[m][d]);
            den[m] += (bm == m) ? sg : 0.f;
        }
    }

    int wave = t >> 6, lane = t & 63;
#pragma unroll
    for (int m = 0; m < 4; ++m) {
#pragma unroll
        for (int d = 0; d < 32; ++d) {
            float v_ = acc[m][d];
#pragma unroll
            for (int off = 32; off >= 1; off >>= 1) v_ += __shfl_xor(v_, off, 64);
            if (lane == 0) wred[wave][m * 32 + d] = v_;
        }
        float dv = den[m];
#pragma unroll
        for (int off = 32; off >= 1; off >>= 1) dv += __shfl_xor(dv, off, 64);
        if (lane == 0) wred[wave][128 + m] = dv;
    }
    __syncthreads();
    if (t < 132) {
        partial[((size_t)be * 9 + chunk) * 136 + t] =
            wred[0][t] + wred[1][t] + wred[2][t] + wred[3][t];
    }
}

// ---------------------------------------------------------------------------
// cluster_dispatch: grid (9, 128). Re-reduce partials -> agg, write op + map.
// ---------------------------------------------------------------------------
__global__ __launch_bounds__(256) void cluster_dispatch(const float* __restrict__ sgv,
                                                        const unsigned char* __restrict__ idxg,
                                                        const float* __restrict__ partial,
                                                        ushort* __restrict__ op,
                                                        float* __restrict__ mapo) {
    __shared__ float tot[136];
    __shared__ float agg[4][32];
    int chunk = blockIdx.x, be = blockIdx.y;
    int b = be >> 3, e = be & 7;
    int t = threadIdx.x;
    if (t < 132) {
        float s = 0.f;
#pragma unroll
        for (int c2 = 0; c2 < 9; ++c2) s += partial[((size_t)be * 9 + c2) * 136 + t];
        tot[t] = s;
    }
    __syncthreads();
    if (t < 128) agg[t >> 5][t & 31] = tot[t] / (tot[128 + (t >> 5)] + 1.0f);
    __syncthreads();
    const float* sgb = sgv + (size_t)be * NPIX;
    const unsigned char* ib = idxg + (size_t)be * NPIX;
    ushort* opb = op + (size_t)b * NPIX * DD + e * 32;
    int n0 = chunk * 1024;
#pragma unroll
    for (int p = 0; p < 4; ++p) {
        int n = n0 + p * 256 + t;
        float sg = sgb[n];
        int m = ib[n];
        const float* ag = agg[m];
        unsigned wds[16];
#pragma unroll
        for (int d2 = 0; d2 < 16; ++d2)
            wds[d2] = (unsigned)f2b(sg * ag[2 * d2]) | ((unsigned)f2b(sg * ag[2 * d2 + 1]) << 16);
        uint4* dst = (uint4*)(opb + (size_t)n * DD);
        dst[0] = make_uint4(wds[0], wds[1], wds[2], wds[3]);
        dst[1] = make_uint4(wds[4], wds[5], wds[6], wds[7]);
        dst[2] = make_uint4(wds[8], wds[9], wds[10], wds[11]);
        dst[3] = make_uint4(wds[12], wds[13], wds[14], wds[15]);
    }
    if (be == 0) {
#pragma unroll
        for (int p = 0; p < 4; ++p) {
            int n = n0 + p * 256 + t;
            mapo[n] = (float)ib[n];
        }
    }
}

// ---------------------------------------------------------------------------
// gemm_p: out[b][o][n] f32 = Wp * op + bp
// ---------------------------------------------------------------------------
__global__ __launch_bounds__(256, 2) void gemm_p(const ushort* __restrict__ wb,
                                                 const float* __restrict__ bpp,
                                                 const ushort* __restrict__ opm,
                                                 float* __restrict__ out) {
    __shared__ ushort lA[128 * 32];
    __shared__ ushort lB[128 * 32];
    int nt = blockIdx.x, mt = blockIdx.y, b = blockIdx.z;
    int t = threadIdx.x;
    int wave = t >> 6, lane = t & 63;
    int wr = wave >> 1, wc = wave & 1;
    const ushort* A = wb + 131072 + (size_t)mt * 128 * 256;  // Wp
    const ushort* Bp = opm + (size_t)b * NPIX * DD + (size_t)nt * 128 * DD;
    f32x4 acc[4][4] = {};
    gemm_main(A, Bp, lA, lB, acc, wr, wc, lane, wave, t);

    int l15 = lane & 15, rg = lane >> 4;
#pragma unroll
    for (int i = 0; i < 4; ++i) {
        int o = mt * 128 + wr * 64 + i * 16 + rg * 4;
        float bi0 = bpp[o + 0], bi1 = bpp[o + 1], bi2 = bpp[o + 2], bi3 = bpp[o + 3];
#pragma unroll
        for (int j = 0; j < 4; ++j) {
            int n = nt * 128 + wc * 64 + j * 16 + l15;
            size_t base = ((size_t)b * 256 + o) * NPIX + n;
            out[base + 0 * (size_t)NPIX] = acc[i][j][0] + bi0;
            out[base + 1 * (size_t)NPIX] = acc[i][j][1] + bi1;
            out[base + 2 * (size_t)NPIX] = acc[i][j][2] + bi2;
            out[base + 3 * (size_t)NPIX] = acc[i][j][3] + bi3;
        }
    }
}

// ---------------------------------------------------------------------------
extern "C" void kernel_launch(void* const* d_in, const int* in_sizes, int n_in,
                              void* d_out, int out_size, void* d_ws, size_t ws_size,
                              hipStream_t stream) {
    const float* x   = (const float*)d_in[0];
    const float* Wf  = (const float*)d_in[1];
    const float* bfp = (const float*)d_in[2];
    const float* Wv  = (const float*)d_in[3];
    const float* bvp = (const float*)d_in[4];
    const float* Wp  = (const float*)d_in[5];
    const float* bpp = (const float*)d_in[6];
    const float* al  = (const float*)d_in[7];
    const float* bt  = (const float*)d_in[8];
    const float* ce  = (const float*)d_in[9];
    float* out = (float*)d_out;

    // Workspace (bytes):
    //   xT (bf16, 75.5MB) -- reused as op after gemm_fv consumes it
    //   wb | G | gb | idxg | zbest(->sg in-place) | partial
    char* ws = (char*)d_ws;
    ushort* xT   = (ushort*)ws;                                  // 75,497,472 B
    ushort* op   = xT;
    ushort* wbuf = (ushort*)(ws + 75497472);                     //    393,216 B
    float*  G    = (float*)(ws + 75890688);                      //     32,768 B
    float*  gb   = (float*)(ws + 75923456);                      //        256 B
    unsigned char* idxg = (unsigned char*)(ws + 75923712);       //  1,179,648 B
    float*  zbest = (float*)(ws + 77103360);                     //  4,718,592 B
    float*  partial = (float*)(ws + 81821952);                   //    626,688 B -> 82,448,640 total

    // fv (bf16, 151MB) lives in d_out; fully consumed before gemm_p overwrites.
    ushort* fv = (ushort*)d_out;
    float* mapo = out + (size_t)BB * DD * NPIX;

    cvt_kernel<<<dim3(192), 256, 0, stream>>>(Wf, Wv, Wp, wbuf);
    prep_kernel<<<dim3(1), 256, 0, stream>>>(Wf, bfp, ce, G, gb);
    tr_kernel<<<dim3(144, 4, BB), 256, 0, stream>>>(x, xT);
    gmap_kernel<<<dim3(36, BB), 256, 0, stream>>>(x, G, gb, al, idxg, zbest);
    gemm_fv<<<dim3(72, 4, BB), 256, 0, stream>>>(wbuf, bfp, bvp, xT, fv);
    cluster_reduce<<<dim3(9, 128), 256, 0, stream>>>(fv, idxg, zbest, bt, partial);
    cluster_dispatch<<<dim3(9, 128), 256, 0, stream>>>(zbest, idxg, partial, op, mapo);
    gemm_p<<<dim3(72, 2, BB), 256, 0, stream>>>(wbuf, bpp, op, out);
}